// Round 20
// baseline (74.158 us; speedup 1.0000x reference)
//
#include <hip/hip_runtime.h>

// SSIM fused: [16,1,1024,1024] fp32, 11-tap separable Gaussian.
// Cross-stage software pipeline INSIDE each wave (no barriers, no state dup):
// per-wave dbuf slabs (2 x 8 KB); iteration st runs 8 interleaved chunks of
//   { 2-3 ds_read_b128 of H(st) from slab-old }   (latency hidden below)
//   { V-row of stage st+1 -> slab-new (44 FMA) }  (independent of H(st))
//   { prefetch row of stage st+2 into pa/pb }     (VMEM hides under stage)
//   { H FMAs for this chunk's reads }
// One basic block per chunk -> scheduler overlaps VALU/DS/VMEM with ~2
// resident waves/SIMD. Tile: 64 cols x 64 rows/wave; H mapping q=lane>>3,
// run=lane&7, S0=run<7?7run:47 (slot-stride-7 reads: conflict-free).
// Scalar f4 math (r18: pk = same VALU cycles). No launch_bounds cap (r5/r6).
// Deterministic reduction: per-wave partial -> finalize -> d_out[0].

typedef float f4 __attribute__((ext_vector_type(4)));

#define W      1024
#define H      1024
#define NIMG   16
#define HALO   5
#define TW     64                  // input cols per wave tile (LDS slots)
#define TOW    54                  // output cols per wave tile
#define RPS    8                   // rows per stage
#define NSTG   8                   // stages per wave
#define TH     (RPS*NSTG)          // 64 output rows per wave
#define NTX    19                  // ceil(1024/54)
#define NTY    (H/TH)              // 16
#define WPB    2                   // waves per block
#define BX     (WPB*64)            // 128 threads
#define NWAVE  (NTX*NTY*NIMG)      // 4864
#define NBLK   (NWAVE/WPB)         // 2432

template<bool INT>
__device__ __forceinline__ void pf_row(const float* __restrict__ p1,
                                       const float* __restrict__ p2,
                                       int j, int c, bool cOK,
                                       float& a, float& b)
{
    if (INT) {
        a = p1[(size_t)j * W + c];
        b = p2[(size_t)j * W + c];
    } else {
        const bool ok = cOK && ((unsigned)j < H);
        a = ok ? p1[(size_t)j * W + c] : 0.0f;
        b = ok ? p2[(size_t)j * W + c] : 0.0f;
    }
}

__device__ __forceinline__ f4 pack_ch(float a, float b)
{
    f4 v;
    v.x = a; v.y = b;
    v.z = fmaf(a, a, b * b);
    v.w = a * b;
    return v;
}

// SSIM epilogue over the 7 h-blurred outputs of one stage-row.
template<bool INT>
__device__ __forceinline__ float ssim_epi(const f4 (&o)[7], int run, int S0,
                                          int obase)
{
    float s = 0.0f;
    const float C1f = 0.0001f, C2f = 0.0009f;
#pragma unroll
    for (int oo = 0; oo < 7; ++oo) {
        const int rel = S0 + oo;
        const bool valid = ((run < 7) || (oo >= 2)) &&   // run7 re-covers run6
                           (INT || (obase + rel) < W);
        if (valid) {
            const float m1 = o[oo].x, m2 = o[oo].y;
            const float qq = o[oo].z, pp = o[oo].w;
            const float mu12 = m1 * m2, m1s = m1 * m1, m2s = m2 * m2;
            const float s12 = pp - mu12;
            const float ssq = qq - m1s - m2s;
            const float num = (2.f * mu12 + C1f) * (2.f * s12 + C2f);
            const float den = (m1s + m2s + C1f) * (ssq + C2f);
            s += num * __builtin_amdgcn_rcpf(den);
        }
    }
    return s;
}

template<bool INT>
__device__ float wave_tile(const float* __restrict__ p1,
                           const float* __restrict__ p2,
                           const float* __restrict__ w,
                           int cb, int r0, int lane, int obase,
                           f4 (*lds)[RPS][TW])
{
    const int  c   = cb + lane;
    const bool cOK = INT || ((unsigned)c < W);

    // ring[1..10] <- rows r0-5 .. r0+4
    f4 ring[11];
#pragma unroll
    for (int k = 0; k < 10; ++k) {
        float a, b;
        pf_row<INT>(p1, p2, r0 - HALO + k, c, cOK, a, b);
        ring[k + 1] = pack_ch(a, b);
    }

    const int q   = lane >> 3;
    const int run = lane & 7;
    const int S0  = (run < 7) ? 7 * run : 47;

    // prefetch stage 0; V(0) -> slab 0; prefetch stage 1
    float pa[RPS], pb[RPS];
#pragma unroll
    for (int rr = 0; rr < RPS; ++rr)
        pf_row<INT>(p1, p2, r0 + HALO + rr, c, cOK, pa[rr], pb[rr]);
#pragma unroll
    for (int rr = 0; rr < RPS; ++rr) {
#pragma unroll
        for (int k = 0; k < 10; ++k) ring[k] = ring[k + 1];
        ring[10] = pack_ch(pa[rr], pb[rr]);
        f4 acc = w[5] * ring[5];
#pragma unroll
        for (int k = 0; k < 5; ++k)
            acc += w[k] * (ring[k] + ring[10 - k]);
        lds[0][rr][lane] = acc;
    }
#pragma unroll
    for (int rr = 0; rr < RPS; ++rr)
        pf_row<INT>(p1, p2, r0 + RPS + HALO + rr, c, cOK, pa[rr], pb[rr]);

    float tsum = 0.0f;

    // ---- merged pipeline: H(st) || V(st+1) || pf(st+2) ----
    for (int st = 0; st < NSTG - 1; ++st) {
        const f4 (*ob)[TW] = (const f4 (*)[TW])lds[st & 1];
        f4 (*nb)[TW] = lds[(st + 1) & 1];
        const int  pfrow  = r0 + (st + 2) * RPS + HALO;
        const bool lastpf = (st + 2 >= NSTG);

        f4 o[7] = {};

#pragma unroll
        for (int rr = 0; rr < RPS; ++rr) {
            const int i0 = 2 * rr;
            const int i1 = (rr == 7) ? 17 : (2 * rr + 2);

            // H reads for this chunk (issue early; consumed after V math)
            f4 u[3];
#pragma unroll
            for (int i = 0; i < 3; ++i)
                if (i0 + i < i1)
                    u[i] = ob[q][S0 + i0 + i];

            // V row rr of stage st+1 (independent of H(st))
#pragma unroll
            for (int k = 0; k < 10; ++k) ring[k] = ring[k + 1];
            ring[10] = pack_ch(pa[rr], pb[rr]);
            f4 acc = w[5] * ring[5];
#pragma unroll
            for (int k = 0; k < 5; ++k)
                acc += w[k] * (ring[k] + ring[10 - k]);
            nb[rr][lane] = acc;

            // prefetch stage st+2 row rr into just-consumed pa/pb
            {
                const int j = lastpf ? r0 : (pfrow + rr);
                pf_row<INT>(p1, p2, j, c, cOK, pa[rr], pb[rr]);
            }

            // H FMAs for this chunk's reads
#pragma unroll
            for (int i = 0; i < 3; ++i) {
                const int ii = i0 + i;
                if (ii < i1) {
#pragma unroll
                    for (int oo = 0; oo < 7; ++oo) {
                        const int k = ii - oo;
                        if (k >= 0 && k < 11)
                            o[oo] += w[k] * u[i];
                    }
                }
            }
        }

        tsum += ssim_epi<INT>(o, run, S0, obase);
    }

    // ---- final stage: H only ----
    {
        const f4 (*ob)[TW] = (const f4 (*)[TW])lds[(NSTG - 1) & 1];
        f4 o[7] = {};
#pragma unroll
        for (int i = 0; i < 17; ++i) {
            const f4 u = ob[q][S0 + i];
#pragma unroll
            for (int oo = 0; oo < 7; ++oo) {
                const int k = i - oo;
                if (k >= 0 && k < 11)
                    o[oo] += w[k] * u;
            }
        }
        tsum += ssim_epi<INT>(o, run, S0, obase);
    }

    return tsum;
}

__global__ __launch_bounds__(BX) void ssim_main(const float* __restrict__ img1,
                                                const float* __restrict__ img2,
                                                const float* __restrict__ win,
                                                float* __restrict__ partials)
{
    __shared__ f4 lds[WPB][2][RPS][TW];      // 2 waves x 2 x 8 KB = 32 KB

    const int t    = threadIdx.x;
    const int wid  = t >> 6;
    const int lane = t & 63;
    const int gw   = blockIdx.x * WPB + wid;

    // gw -> (img, gy, tx); tx fastest for L2 halo sharing
    const int img = gw / (NTX * NTY);
    const int rem = gw - img * (NTX * NTY);
    const int gy  = rem / NTX;
    const int tx  = rem - gy * NTX;

    const int cb    = tx * TOW - HALO;
    const int obase = tx * TOW;
    const int r0    = gy * TH;

    const float* __restrict__ p1 = img1 + (size_t)img * (size_t)(W * H);
    const float* __restrict__ p2 = img2 + (size_t)img * (size_t)(W * H);

    float w[11];
#pragma unroll
    for (int k = 0; k < 11; ++k)
        w[k] = __int_as_float(__builtin_amdgcn_readfirstlane(__float_as_int(win[k])));

    const bool interior = (cb >= 0) && (cb + TW <= W) &&
                          (r0 >= HALO) && (r0 + TH - 1 + HALO < H);

    float tsum = interior
               ? wave_tile<true >(p1, p2, w, cb, r0, lane, obase, lds[wid])
               : wave_tile<false>(p1, p2, w, cb, r0, lane, obase, lds[wid]);

    // wave-private reduction; one store per wave — no barrier
#pragma unroll
    for (int off = 32; off > 0; off >>= 1)
        tsum += __shfl_down(tsum, off, 64);

    if (lane == 0)
        partials[gw] = tsum;
}

__global__ __launch_bounds__(256) void ssim_finalize(const float* __restrict__ partials,
                                                     float* __restrict__ out)
{
    double s = 0.0;
    for (int i = threadIdx.x; i < NWAVE; i += 256) s += (double)partials[i];
#pragma unroll
    for (int off = 32; off > 0; off >>= 1)
        s += __shfl_down(s, off, 64);

    __shared__ double ws[4];
    if ((threadIdx.x & 63) == 0) ws[threadIdx.x >> 6] = s;
    __syncthreads();
    if (threadIdx.x == 0) {
        const double tt = ws[0] + ws[1] + ws[2] + ws[3];
        out[0] = (float)(tt / (double)((size_t)NIMG * W * H));
    }
}

extern "C" void kernel_launch(void* const* d_in, const int* in_sizes, int n_in,
                              void* d_out, int out_size, void* d_ws, size_t ws_size,
                              hipStream_t stream)
{
    const float* img1 = (const float*)d_in[0];
    const float* img2 = (const float*)d_in[1];
    const float* win  = (const float*)d_in[2];
    float* partials   = (float*)d_ws;
    float* out        = (float*)d_out;

    ssim_main<<<NBLK, BX, 0, stream>>>(img1, img2, win, partials);
    ssim_finalize<<<1, 256, 0, stream>>>(partials, out);
}